// Round 4
// baseline (228.004 us; speedup 1.0000x reference)
//
#include <hip/hip_runtime.h>

// Joint bilateral filter 5x5, SAME zero padding.
// template: (1,3,1080,1920) f32 planar; vector: (1,2,1080,1920) f32 planar.
// out: (1,2,1080,1920) f32.
//
// Round 7: round-4's verified ALGORITHM (2 output rows/thread, TS_Y=30,
// LDS_W=76 padded stride, folded coeff) in round-3's verified CODE SHAPE
// (two-phase register staging, no lambdas, constant-indexed arrays only).
//  - round-4 lesson: by-reference-captured lambdas -> arrays demoted to
//    scratch (WRITE_SIZE 185MB, 3.6x slower). Everything here is inlined.
//  - rounds-5/6 lesson: global_load_lds staging produced wrong results
//    twice (mechanism unresolved); reverted to reg staging permanently.
//  - centers loaded as 12 explicit 8B-aligned float2 LDS reads (2-way bank
//    pattern, free per m136), independent of row iteration order.
//  - 6-row window feeds both output rows: 60 b128 + 12 b64 LDS reads per
//    8 pixels (vs round-3's 50 b128 + 12 b32 per 4 pixels).

#define IMG_H 1080
#define IMG_W 1920
#define IMG_HW (IMG_H * IMG_W)
#define TS_X 64
#define TS_Y 30
#define HALO_H 34      // TS_Y + 4
#define HALO_W 68      // image cols x0-2 .. x0+65 (exactly what is read)
#define LDS_W 76       // padded row stride (dwords): 12-bank shift/row
#define NCH 5
#define F4_PER_ROW 17            // 68/4
#define F4_PER_CH (F4_PER_ROW * HALO_H)   // 578

typedef float f4u __attribute__((ext_vector_type(4), aligned(4)));

__global__ __launch_bounds__(256, 3)
void jbf_kernel(const float* __restrict__ tpl,
                const float* __restrict__ vec,
                float* __restrict__ out) {
    constexpr float SIDIV = 50.0f;   // 1/(2*sigma_intensity^2)
    // coeff = clip(1 - |(-0.125) - id*50|, 0, 1) = max(0.875 - 50*id, 0), id >= 0
    // (verified correct in round 4's passing run)

    __shared__ __align__(16) float smem[NCH][HALO_H][LDS_W];

    const int tid = threadIdx.x;
    const int bx = blockIdx.x, by = blockIdx.y;
    const int x0 = bx * TS_X;
    const int y0 = by * TS_Y;

    // interior: halo rows y0-2..y0+31, cols x0-2..x0+65 fully in-bounds
    const bool interior = (bx >= 1) & (bx <= 28) & (by >= 1) & (by <= 34);

    if (interior) {
        const int tl = (y0 - 2) * IMG_W + (x0 - 2);
        // phase 1: issue all 15 global float4 loads (round-3 two-phase pattern)
        f4u v[15];
#pragma unroll
        for (int ch = 0; ch < NCH; ++ch) {
            const float* __restrict__ src =
                (ch < 3) ? (tpl + ch * IMG_HW) : (vec + (ch - 3) * IMG_HW);
#pragma unroll
            for (int it = 0; it < 3; ++it) {
                int idx = tid + it * 256;
                idx = (idx < F4_PER_CH) ? idx : 0;       // clamp: load stays in-bounds
                const int r  = idx / F4_PER_ROW;
                const int c4 = idx - r * F4_PER_ROW;
                v[ch * 3 + it] = *(const f4u*)(src + tl + r * IMG_W + c4 * 4);
            }
        }
        // phase 2: LDS stores
#pragma unroll
        for (int ch = 0; ch < NCH; ++ch) {
#pragma unroll
            for (int it = 0; it < 3; ++it) {
                const int idx = tid + it * 256;
                if (idx < F4_PER_CH) {
                    const int r  = idx / F4_PER_ROW;
                    const int c4 = idx - r * F4_PER_ROW;
                    float4* d = (float4*)&smem[ch][r][c4 * 4];
                    d->x = v[ch * 3 + it].x; d->y = v[ch * 3 + it].y;
                    d->z = v[ch * 3 + it].z; d->w = v[ch * 3 + it].w;
                }
            }
        }
    } else {
        // border: scalar bounds-checked staging with zero fill
#pragma unroll
        for (int c = 0; c < NCH; ++c) {
            const float* __restrict__ src =
                (c < 3) ? (tpl + c * IMG_HW) : (vec + (c - 3) * IMG_HW);
            for (int i = tid; i < HALO_H * HALO_W; i += 256) {
                const int r   = i / HALO_W;
                const int col = i - r * HALO_W;
                const int gy  = y0 + r - 2;
                const int gx  = x0 + col - 2;
                float val = 0.0f;
                if (gy >= 0 && gy < IMG_H && gx >= 0 && gx < IMG_W)
                    val = src[gy * IMG_W + gx];
                smem[c][r][col] = val;
            }
        }
    }
    __syncthreads();

    const int tx  = tid & 15;   // 16 threads across
    const int tyq = tid >> 4;   // 0..15; rows 0..14 compute

    if (tyq < 15) {
        const int lx = tx * 4;        // halo col of px0 is lx+2
        const int rA = tyq * 2;       // output rows y0+rA (A), y0+rA+1 (B)

        // centers: halo cols lx+2..lx+5 at rows rA+2 (A) and rA+3 (B).
        // float2 loads, 8B-aligned (lx even).
        float cA0[4], cA1[4], cA2[4], cB0[4], cB1[4], cB2[4];
        {
            const float2 pA0 = *(const float2*)&smem[0][rA + 2][lx + 2];
            const float2 qA0 = *(const float2*)&smem[0][rA + 2][lx + 4];
            const float2 pA1 = *(const float2*)&smem[1][rA + 2][lx + 2];
            const float2 qA1 = *(const float2*)&smem[1][rA + 2][lx + 4];
            const float2 pA2 = *(const float2*)&smem[2][rA + 2][lx + 2];
            const float2 qA2 = *(const float2*)&smem[2][rA + 2][lx + 4];
            cA0[0] = pA0.x; cA0[1] = pA0.y; cA0[2] = qA0.x; cA0[3] = qA0.y;
            cA1[0] = pA1.x; cA1[1] = pA1.y; cA1[2] = qA1.x; cA1[3] = qA1.y;
            cA2[0] = pA2.x; cA2[1] = pA2.y; cA2[2] = qA2.x; cA2[3] = qA2.y;
            const float2 pB0 = *(const float2*)&smem[0][rA + 3][lx + 2];
            const float2 qB0 = *(const float2*)&smem[0][rA + 3][lx + 4];
            const float2 pB1 = *(const float2*)&smem[1][rA + 3][lx + 2];
            const float2 qB1 = *(const float2*)&smem[1][rA + 3][lx + 4];
            const float2 pB2 = *(const float2*)&smem[2][rA + 3][lx + 2];
            const float2 qB2 = *(const float2*)&smem[2][rA + 3][lx + 4];
            cB0[0] = pB0.x; cB0[1] = pB0.y; cB0[2] = qB0.x; cB0[3] = qB0.y;
            cB1[0] = pB1.x; cB1[1] = pB1.y; cB1[2] = qB1.x; cB1[3] = qB1.y;
            cB2[0] = pB2.x; cB2[1] = pB2.y; cB2[2] = qB2.x; cB2[3] = qB2.y;
        }

        float n0A[4] = {0.f, 0.f, 0.f, 0.f}, n1A[4] = {0.f, 0.f, 0.f, 0.f};
        float n0B[4] = {0.f, 0.f, 0.f, 0.f}, n1B[4] = {0.f, 0.f, 0.f, 0.f};
        float dnA[4] = {0.f, 0.f, 0.f, 0.f}, dnB[4] = {0.f, 0.f, 0.f, 0.f};

        // 6 window rows rA..rA+5; row A consumes r=0..4 (dy=r),
        // row B consumes r=1..5 (dy=r-1). Fully unrolled, straight-line.
#pragma unroll
        for (int r = 0; r < 6; ++r) {
            const int hr = rA + r;
            const float4 a0  = *(const float4*)&smem[0][hr][lx];
            const float4 b0  = *(const float4*)&smem[0][hr][lx + 4];
            const float4 a1  = *(const float4*)&smem[1][hr][lx];
            const float4 b1  = *(const float4*)&smem[1][hr][lx + 4];
            const float4 a2  = *(const float4*)&smem[2][hr][lx];
            const float4 b2  = *(const float4*)&smem[2][hr][lx + 4];
            const float4 av0 = *(const float4*)&smem[3][hr][lx];
            const float4 bv0 = *(const float4*)&smem[3][hr][lx + 4];
            const float4 av1 = *(const float4*)&smem[4][hr][lx];
            const float4 bv1 = *(const float4*)&smem[4][hr][lx + 4];

            const float w0[8]  = {a0.x, a0.y, a0.z, a0.w, b0.x, b0.y, b0.z, b0.w};
            const float w1[8]  = {a1.x, a1.y, a1.z, a1.w, b1.x, b1.y, b1.z, b1.w};
            const float w2[8]  = {a2.x, a2.y, a2.z, a2.w, b2.x, b2.y, b2.z, b2.w};
            const float wv0[8] = {av0.x, av0.y, av0.z, av0.w, bv0.x, bv0.y, bv0.z, bv0.w};
            const float wv1[8] = {av1.x, av1.y, av1.z, av1.w, bv1.x, bv1.y, bv1.z, bv1.w};

            if (r < 5) {   // output row A taps, dy = r
#pragma unroll
                for (int dx = 0; dx < 5; ++dx) {
#pragma unroll
                    for (int px = 0; px < 4; ++px) {
                        const int k = dx + px;           // halo col lx+k, k in 0..7
                        const float d0 = cA0[px] - w0[k];
                        const float d1 = cA1[px] - w1[k];
                        const float d2 = cA2[px] - w2[k];
                        const float id = fmaf(d0, d0, fmaf(d1, d1, d2 * d2));
                        const float coeff = fmaxf(fmaf(id, -SIDIV, 0.875f), 0.0f);
                        n0A[px] = fmaf(wv0[k], coeff, n0A[px]);
                        n1A[px] = fmaf(wv1[k], coeff, n1A[px]);
                        dnA[px] += coeff;
                    }
                }
            }
            if (r > 0) {   // output row B taps, dy = r-1
#pragma unroll
                for (int dx = 0; dx < 5; ++dx) {
#pragma unroll
                    for (int px = 0; px < 4; ++px) {
                        const int k = dx + px;
                        const float d0 = cB0[px] - w0[k];
                        const float d1 = cB1[px] - w1[k];
                        const float d2 = cB2[px] - w2[k];
                        const float id = fmaf(d0, d0, fmaf(d1, d1, d2 * d2));
                        const float coeff = fmaxf(fmaf(id, -SIDIV, 0.875f), 0.0f);
                        n0B[px] = fmaf(wv0[k], coeff, n0B[px]);
                        n1B[px] = fmaf(wv1[k], coeff, n1B[px]);
                        dnB[px] += coeff;
                    }
                }
            }
        }

        const int gx  = x0 + lx;
        const int gyA = y0 + rA;      // exact tiling: gyA+1 <= 1079, no mask

        float4 oA0, oA1, oB0, oB1;
        {
            const float r0 = __builtin_amdgcn_rcpf(dnA[0]);
            const float r1 = __builtin_amdgcn_rcpf(dnA[1]);
            const float r2 = __builtin_amdgcn_rcpf(dnA[2]);
            const float r3 = __builtin_amdgcn_rcpf(dnA[3]);
            oA0.x = n0A[0] * r0; oA0.y = n0A[1] * r1; oA0.z = n0A[2] * r2; oA0.w = n0A[3] * r3;
            oA1.x = n1A[0] * r0; oA1.y = n1A[1] * r1; oA1.z = n1A[2] * r2; oA1.w = n1A[3] * r3;
        }
        {
            const float r0 = __builtin_amdgcn_rcpf(dnB[0]);
            const float r1 = __builtin_amdgcn_rcpf(dnB[1]);
            const float r2 = __builtin_amdgcn_rcpf(dnB[2]);
            const float r3 = __builtin_amdgcn_rcpf(dnB[3]);
            oB0.x = n0B[0] * r0; oB0.y = n0B[1] * r1; oB0.z = n0B[2] * r2; oB0.w = n0B[3] * r3;
            oB1.x = n1B[0] * r0; oB1.y = n1B[1] * r1; oB1.z = n1B[2] * r2; oB1.w = n1B[3] * r3;
        }

        *(float4*)(out + gyA * IMG_W + gx)                 = oA0;
        *(float4*)(out + IMG_HW + gyA * IMG_W + gx)        = oA1;
        *(float4*)(out + (gyA + 1) * IMG_W + gx)           = oB0;
        *(float4*)(out + IMG_HW + (gyA + 1) * IMG_W + gx)  = oB1;
    }
}

extern "C" void kernel_launch(void* const* d_in, const int* in_sizes, int n_in,
                              void* d_out, int out_size, void* d_ws, size_t ws_size,
                              hipStream_t stream) {
    const float* tpl = (const float*)d_in[0];
    const float* vec = (const float*)d_in[1];
    float* out = (float*)d_out;

    dim3 grid(IMG_W / TS_X, IMG_H / TS_Y);   // 30 x 36
    jbf_kernel<<<grid, 256, 0, stream>>>(tpl, vec, out);
}

// Round 5
// 111.394 us; speedup vs baseline: 2.0468x; 2.0468x over previous
//
#include <hip/hip_runtime.h>

// Joint bilateral filter 5x5, SAME zero padding.
// template: (1,3,1080,1920) f32 planar; vector: (1,2,1080,1920) f32 planar.
// out: (1,2,1080,1920) f32.
//
// Round 8: round-3 baseline (43 us/dispatch, VGPR 88, zero scratch) verbatim,
// plus exactly two verified micro-deltas:
//  1) dy order {2,0,1,3,4}; centers extracted from the dy=2 b128 window reads
//     (w[p+2]) -> removes the 12 stride-4 ds_read_b32 center loads, which were
//     an 8-way bank conflict (all 4 row-groups of a wave on bank set {0,4,..,28}).
//  2) coeff = max(0.875 - 50*id, 0) with explicit fmaf (id >= 0 folds away the
//     abs and upper clamp; verified bit-correct in rounds 4/7 passing runs).
// Closed directions (measured): 2-rows/thread + __launch_bounds__(256,3) ->
// arrays demoted to scratch (WRITE 185-202 MB, 3.7x slower) in BOTH code
// shapes; global_load_lds staging -> wrong results twice (mechanism unresolved).

#define IMG_H 1080
#define IMG_W 1920
#define IMG_HW (IMG_H * IMG_W)
#define TS_X 64      // tile width  (pixels)
#define TS_Y 16      // tile height (pixels)
#define HALO_H 20    // TS_Y + 4
#define HALO_W 72    // TS_X + 8
#define NCH 5
#define F4_PER_ROW 18            // 72/4
#define F4_PER_CH  (F4_PER_ROW * HALO_H)   // 360

typedef float f4u __attribute__((ext_vector_type(4), aligned(4)));

__global__ __launch_bounds__(256)
void jbf_kernel(const float* __restrict__ tpl,
                const float* __restrict__ vec,
                float* __restrict__ out) {
    constexpr float SIDIV = 50.0f;    // 1/(2*sigma_intensity^2)
    // coeff = clip(1 - |(-0.125) - id*50|, 0, 1) = max(0.875 - 50*id, 0), id >= 0

    __shared__ __align__(16) float smem[NCH][HALO_H][HALO_W];

    const int tid = threadIdx.x;
    const int x0  = blockIdx.x * TS_X;
    const int y0  = blockIdx.y * TS_Y;

    // interior: whole 20x72 halo window in-bounds (no zero padding needed)
    const bool interior = (blockIdx.x >= 1) & (blockIdx.x <= 28) &
                          (blockIdx.y >= 1) & (blockIdx.y <= 66);

    if (interior) {
        // flat f4 index per channel: idx in [0,360); row=idx/18, col4=idx%18
        const int i0  = tid;
        const int i1  = tid + 256;
        const bool p1 = (i1 < F4_PER_CH);          // tid < 104
        const int i1c = p1 ? i1 : 0;
        const int r0 = i0 / F4_PER_ROW, c0 = i0 - r0 * F4_PER_ROW;
        const int r1 = i1c / F4_PER_ROW, c1 = i1c - r1 * F4_PER_ROW;
        const int off0 = r0 * IMG_W + c0 * 4;
        const int off1 = r1 * IMG_W + c1 * 4;
        const int tl   = (y0 - 2) * IMG_W + (x0 - 2);   // top-left of halo

        f4u v[2 * NCH];
#pragma unroll
        for (int ch = 0; ch < NCH; ++ch) {
            const float* __restrict__ src =
                (ch < 3) ? (tpl + ch * IMG_HW) : (vec + (ch - 3) * IMG_HW);
            v[2 * ch]     = *(const f4u*)(src + tl + off0);
            v[2 * ch + 1] = *(const f4u*)(src + tl + off1);
        }
#pragma unroll
        for (int ch = 0; ch < NCH; ++ch) {
            float4* d0 = (float4*)&smem[ch][r0][c0 * 4];
            d0->x = v[2 * ch].x; d0->y = v[2 * ch].y;
            d0->z = v[2 * ch].z; d0->w = v[2 * ch].w;
            if (p1) {
                float4* d1 = (float4*)&smem[ch][r1][c1 * 4];
                d1->x = v[2 * ch + 1].x; d1->y = v[2 * ch + 1].y;
                d1->z = v[2 * ch + 1].z; d1->w = v[2 * ch + 1].w;
            }
        }
    } else {
        // border: scalar bounds-checked staging with zero fill
#pragma unroll
        for (int c = 0; c < NCH; ++c) {
            const float* __restrict__ src =
                (c < 3) ? (tpl + c * IMG_HW) : (vec + (c - 3) * IMG_HW);
#pragma unroll
            for (int i = tid; i < HALO_H * HALO_W; i += 256) {
                const int r   = i / HALO_W;
                const int col = i - r * HALO_W;
                const int gy  = y0 + r - 2;
                const int gx  = x0 + col - 2;
                float val = 0.0f;
                if (gy >= 0 && gy < IMG_H && gx >= 0 && gx < IMG_W)
                    val = src[gy * IMG_W + gx];
                smem[c][r][col] = val;
            }
        }
    }
    __syncthreads();

    const int tx = tid & 15;   // 16 threads across
    const int ty = tid >> 4;   // 16 rows
    const int lx = tx * 4;     // first of 4 pixels this thread owns (halo col lx+2)

    float num0[4] = {0.f, 0.f, 0.f, 0.f};
    float num1[4] = {0.f, 0.f, 0.f, 0.f};
    float den [4] = {0.f, 0.f, 0.f, 0.f};
    float c0[4], c1[4], c2[4];

    // dy order {2,0,1,3,4}: centers come out of the dy=2 window b128 reads
    // (center px p = halo col lx+2+p = w[p+2]). Accumulation order-invariant.
#pragma unroll
    for (int s = 0; s < 5; ++s) {
        constexpr int DYS[5] = {2, 0, 1, 3, 4};
        const int row = ty + DYS[s];
        const float4 a0  = *(const float4*)&smem[0][row][lx];
        const float4 b0  = *(const float4*)&smem[0][row][lx + 4];
        const float4 a1  = *(const float4*)&smem[1][row][lx];
        const float4 b1  = *(const float4*)&smem[1][row][lx + 4];
        const float4 a2  = *(const float4*)&smem[2][row][lx];
        const float4 b2  = *(const float4*)&smem[2][row][lx + 4];
        const float4 av0 = *(const float4*)&smem[3][row][lx];
        const float4 bv0 = *(const float4*)&smem[3][row][lx + 4];
        const float4 av1 = *(const float4*)&smem[4][row][lx];
        const float4 bv1 = *(const float4*)&smem[4][row][lx + 4];

        if (s == 0) {   // dy == 2: centers at halo cols lx+2..lx+5
            c0[0] = a0.z; c0[1] = a0.w; c0[2] = b0.x; c0[3] = b0.y;
            c1[0] = a1.z; c1[1] = a1.w; c1[2] = b1.x; c1[3] = b1.y;
            c2[0] = a2.z; c2[1] = a2.w; c2[2] = b2.x; c2[3] = b2.y;
        }

        const float w0[8]  = {a0.x, a0.y, a0.z, a0.w, b0.x, b0.y, b0.z, b0.w};
        const float w1[8]  = {a1.x, a1.y, a1.z, a1.w, b1.x, b1.y, b1.z, b1.w};
        const float w2[8]  = {a2.x, a2.y, a2.z, a2.w, b2.x, b2.y, b2.z, b2.w};
        const float wv0[8] = {av0.x, av0.y, av0.z, av0.w, bv0.x, bv0.y, bv0.z, bv0.w};
        const float wv1[8] = {av1.x, av1.y, av1.z, av1.w, bv1.x, bv1.y, bv1.z, bv1.w};

#pragma unroll
        for (int dx = 0; dx < 5; ++dx) {
#pragma unroll
            for (int px = 0; px < 4; ++px) {
                const int k = dx + px;           // halo col lx+k
                const float d0 = c0[px] - w0[k];
                const float d1 = c1[px] - w1[k];
                const float d2 = c2[px] - w2[k];
                const float id = fmaf(d0, d0, fmaf(d1, d1, d2 * d2));
                const float coeff = fmaxf(fmaf(id, -SIDIV, 0.875f), 0.0f);
                num0[px] = fmaf(wv0[k], coeff, num0[px]);
                num1[px] = fmaf(wv1[k], coeff, num1[px]);
                den [px] += coeff;
            }
        }
    }

    const int gy = y0 + ty;
    if (gy < IMG_H) {
        const int gx = x0 + lx;
        float4 o0, o1;
        const float r0 = __builtin_amdgcn_rcpf(den[0]);
        const float r1 = __builtin_amdgcn_rcpf(den[1]);
        const float r2 = __builtin_amdgcn_rcpf(den[2]);
        const float r3 = __builtin_amdgcn_rcpf(den[3]);
        o0.x = num0[0] * r0; o0.y = num0[1] * r1; o0.z = num0[2] * r2; o0.w = num0[3] * r3;
        o1.x = num1[0] * r0; o1.y = num1[1] * r1; o1.z = num1[2] * r2; o1.w = num1[3] * r3;
        *(float4*)(out + (size_t)0 * IMG_HW + gy * IMG_W + gx) = o0;
        *(float4*)(out + (size_t)1 * IMG_HW + gy * IMG_W + gx) = o1;
    }
}

extern "C" void kernel_launch(void* const* d_in, const int* in_sizes, int n_in,
                              void* d_out, int out_size, void* d_ws, size_t ws_size,
                              hipStream_t stream) {
    const float* tpl = (const float*)d_in[0];
    const float* vec = (const float*)d_in[1];
    float* out = (float*)d_out;

    dim3 grid(IMG_W / TS_X, (IMG_H + TS_Y - 1) / TS_Y);  // 30 x 68
    jbf_kernel<<<grid, 256, 0, stream>>>(tpl, vec, out);
}